// Round 9
// baseline (75.615 us; speedup 1.0000x reference)
//
#include <hip/hip_runtime.h>
#include <math.h>

#define KBT 2.494338785445972f
#define CHUNK 2048  // f4 elements of one W1 row per block (32KB)
#define L3GRID 64   // blocks in l3out (4 rows each)

typedef float f4 __attribute__((ext_vector_type(4)));

struct F3 { float x, y, z; };
__device__ inline F3 f3sub(F3 a, F3 b) { return {a.x - b.x, a.y - b.y, a.z - b.z}; }
__device__ inline F3 f3cross(F3 a, F3 b) {
    return {a.y * b.z - a.z * b.y, a.z * b.x - a.x * b.z, a.x * b.y - a.y * b.x};
}
__device__ inline float f3dot(F3 a, F3 b) { return a.x * b.x + a.y * b.y + a.z * b.z; }
__device__ inline F3 ldp(const float* __restrict__ p, int i) {
    return {p[3 * i], p[3 * i + 1], p[3 * i + 2]};
}
__device__ inline float dot4(f4 w, f4 v, float acc) {
    return fmaf(w.x, v.x, fmaf(w.y, v.y, fmaf(w.z, v.z, fmaf(w.w, v.w, acc))));
}

// Kernel 1: features x = [cos(angles) (A), cos(dih) (D), sin(dih) (D)]
__global__ __launch_bounds__(256) void feat_kernel(
    const float* __restrict__ pos, const int* __restrict__ aidx,
    const int* __restrict__ didx, float* __restrict__ x, int A, int D) {
    int i = blockIdx.x * blockDim.x + threadIdx.x;
    if (i < A) {
        int i0 = aidx[3 * i], i1 = aidx[3 * i + 1], i2 = aidx[3 * i + 2];
        F3 p0 = ldp(pos, i0), p1 = ldp(pos, i1), p2 = ldp(pos, i2);
        F3 v0 = f3sub(p0, p1), v1 = f3sub(p2, p1);
        float d = f3dot(v0, v1);
        F3 c = f3cross(v0, v1);
        float r = sqrtf(d * d + f3dot(c, c));   // = |v0||v1|
        x[i] = d / r;                            // cos(atan2(|c|, d))
    } else if (i < A + D) {
        int j = i - A;
        int i0 = didx[4 * j], i1 = didx[4 * j + 1], i2 = didx[4 * j + 2], i3 = didx[4 * j + 3];
        F3 p0 = ldp(pos, i0), p1 = ldp(pos, i1), p2 = ldp(pos, i2), p3 = ldp(pos, i3);
        F3 b1v = f3sub(p1, p0), b2v = f3sub(p2, p1), b3v = f3sub(p3, p2);
        F3 n1 = f3cross(b1v, b2v), n2 = f3cross(b2v, b3v);
        float xc = f3dot(n1, n2);                          // cos-like term
        float b2n = sqrtf(f3dot(b2v, b2v));
        F3 cr = f3cross(n1, n2);
        float yc = f3dot(cr, b2v) / b2n;                   // sin-like term
        float r = sqrtf(xc * xc + yc * yc);
        x[A + j] = xc / r;        // cos(dihedral)
        x[A + D + j] = yc / r;    // sin(dihedral)
    }
}

// Kernel 2: y1 partials, linear-sweep layout, 8-deep ILP, nontemporal W1
// (R8 A/B showed nt is 2us faster: 307MB cyclic stream thrashes 256MB L3,
// and nt keeps x/W2/W3 cache-resident instead).
__global__ __launch_bounds__(256) void w1_kernel(
    const float* __restrict__ W1, const float* __restrict__ x,
    float* __restrict__ partial, int F4, int NCH) {
    int c = blockIdx.x, r = blockIdx.y;
    const f4* __restrict__ row = (const f4*)W1 + (size_t)r * F4;
    const f4* __restrict__ xv = (const f4*)x;
    int base = c * CHUNK + (int)threadIdx.x;
    float a0 = 0.0f, a1 = 0.0f, a2 = 0.0f, a3 = 0.0f;
    float a4 = 0.0f, a5 = 0.0f, a6 = 0.0f, a7 = 0.0f;
    if (base + 1792 < F4) {  // full chunk fast path: 8 independent streams
        f4 w0 = __builtin_nontemporal_load(&row[base]);
        f4 w1 = __builtin_nontemporal_load(&row[base + 256]);
        f4 w2 = __builtin_nontemporal_load(&row[base + 512]);
        f4 w3 = __builtin_nontemporal_load(&row[base + 768]);
        f4 w4 = __builtin_nontemporal_load(&row[base + 1024]);
        f4 w5 = __builtin_nontemporal_load(&row[base + 1280]);
        f4 w6 = __builtin_nontemporal_load(&row[base + 1536]);
        f4 w7 = __builtin_nontemporal_load(&row[base + 1792]);
        a0 = dot4(w0, xv[base], a0);
        a1 = dot4(w1, xv[base + 256], a1);
        a2 = dot4(w2, xv[base + 512], a2);
        a3 = dot4(w3, xv[base + 768], a3);
        a4 = dot4(w4, xv[base + 1024], a4);
        a5 = dot4(w5, xv[base + 1280], a5);
        a6 = dot4(w6, xv[base + 1536], a6);
        a7 = dot4(w7, xv[base + 1792], a7);
    } else {
        #pragma unroll
        for (int u = 0; u < 8; ++u) {
            int i = base + u * 256;
            if (i < F4) a0 = dot4(__builtin_nontemporal_load(&row[i]), xv[i], a0);
        }
    }
    float acc = ((a0 + a1) + (a2 + a3)) + ((a4 + a5) + (a6 + a7));
    #pragma unroll
    for (int off = 32; off; off >>= 1) acc += __shfl_down(acc, off);
    __shared__ float lds[4];
    int wave = threadIdx.x >> 6, lane = threadIdx.x & 63;
    if (lane == 0) lds[wave] = acc;
    __syncthreads();
    if (threadIdx.x == 0) partial[r * NCH + c] = lds[0] + lds[1] + lds[2] + lds[3];
}

// Kernel 3: layer 2, one block per output row (parallel W2 fetch). Each block
// redundantly finishes layer 1 from L2-hot partials. Block 0 zeroes the
// l3out ticket (runs strictly before l3out; also fixes 0xAA ws poison).
__global__ __launch_bounds__(256) void l2_kernel(
    const float* __restrict__ partial, const float* __restrict__ b1,
    const float* __restrict__ W2, const float* __restrict__ b2,
    float* __restrict__ xb, unsigned int* __restrict__ ticket, int NCH) {
    __shared__ float xa[256];
    __shared__ float lds[4];
    int t = threadIdx.x, r = blockIdx.x;
    if (r == 0 && t == 0) *ticket = 0u;
    float s = 0.0f;
    #pragma unroll 8
    for (int c = 0; c < NCH; ++c) s += partial[t * NCH + c];
    xa[t] = tanhf(s + b1[t]);
    __syncthreads();
    float v = W2[(r << 8) + t] * xa[t];
    #pragma unroll
    for (int off = 32; off; off >>= 1) v += __shfl_down(v, off);
    if ((t & 63) == 0) lds[t >> 6] = v;
    __syncthreads();
    if (t == 0) xb[r] = tanhf(lds[0] + lds[1] + lds[2] + lds[3] + b2[r]);
}

// Kernel 4: layer 3 + W4 term (64 blocks x 4 rows, parallel W3 fetch), then
// the block taking the LAST ticket reduces all 256 w4terms in fixed index
// order (bitwise deterministic) and writes the scalar output.
__global__ __launch_bounds__(256) void l3out_kernel(
    const float* __restrict__ xb, const float* __restrict__ W3,
    const float* __restrict__ b3, const float* __restrict__ W4,
    float* __restrict__ w4term, unsigned int* __restrict__ ticket,
    float* __restrict__ out) {
    __shared__ float lds[4];
    __shared__ unsigned int rank;
    int t = threadIdx.x;
    float xbt = xb[t];
    int base = blockIdx.x << 2;
    #pragma unroll
    for (int rr = 0; rr < 4; ++rr) {
        int r = base + rr;
        float v = W3[(r << 8) + t] * xbt;
        #pragma unroll
        for (int off = 32; off; off >>= 1) v += __shfl_down(v, off);
        if ((t & 63) == 0) lds[t >> 6] = v;
        __syncthreads();
        if (t == 0) {
            float y = W4[r] * tanhf(lds[0] + lds[1] + lds[2] + lds[3] + b3[r]);
            __hip_atomic_store(&w4term[r], y, __ATOMIC_RELAXED,
                               __HIP_MEMORY_SCOPE_AGENT);
        }
        __syncthreads();
    }
    // release our w4term writes, then take a ticket
    __threadfence();
    if (t == 0) rank = atomicAdd(ticket, 1u);
    __syncthreads();
    if (rank == L3GRID - 1) {  // last block: all other blocks' stores are done
        __threadfence();
        float v = __hip_atomic_load(&w4term[t], __ATOMIC_RELAXED,
                                    __HIP_MEMORY_SCOPE_AGENT);
        #pragma unroll
        for (int off = 32; off; off >>= 1) v += __shfl_down(v, off);
        if ((t & 63) == 0) lds[t >> 6] = v;
        __syncthreads();
        if (t == 0) out[0] = KBT * (lds[0] + lds[1] + lds[2] + lds[3]);
    }
}

extern "C" void kernel_launch(void* const* d_in, const int* in_sizes, int n_in,
                              void* d_out, int out_size, void* d_ws, size_t ws_size,
                              hipStream_t stream) {
    const float* pos  = (const float*)d_in[0];
    const int*   aidx = (const int*)d_in[1];
    const int*   didx = (const int*)d_in[2];
    const float* W1   = (const float*)d_in[3];
    const float* b1   = (const float*)d_in[4];
    const float* W2   = (const float*)d_in[5];
    const float* b2   = (const float*)d_in[6];
    const float* W3   = (const float*)d_in[7];
    const float* b3   = (const float*)d_in[8];
    const float* W4   = (const float*)d_in[9];

    int A = in_sizes[1] / 3;
    int D = in_sizes[2] / 4;
    int F = A + 2 * D;          // 299992, divisible by 4
    int F4 = F >> 2;            // 74998 f4 per row
    int NCH = (F4 + CHUNK - 1) / CHUNK;  // 37

    float* ws = (float*)d_ws;
    float* x = ws;                              // F floats
    float* partial = ws + ((F + 3) & ~3);       // 256*NCH floats
    float* xb = partial + 256 * NCH;            // 256 floats
    float* w4term = xb + 256;                   // 256 floats
    unsigned int* ticket = (unsigned int*)(w4term + 256);

    int total = A + D;
    feat_kernel<<<(total + 255) / 256, 256, 0, stream>>>(pos, aidx, didx, x, A, D);

    dim3 g(NCH, 256);  // chunk fastest -> linear HBM sweep over W1
    w1_kernel<<<g, 256, 0, stream>>>(W1, x, partial, F4, NCH);

    l2_kernel<<<256, 256, 0, stream>>>(partial, b1, W2, b2, xb, ticket, NCH);
    l3out_kernel<<<L3GRID, 256, 0, stream>>>(xb, W3, b3, W4, w4term, ticket,
                                             (float*)d_out);
}

// Round 10
// 71.574 us; speedup vs baseline: 1.0565x; 1.0565x over previous
//
#include <hip/hip_runtime.h>
#include <math.h>

#define KBT 2.494338785445972f
#define CHUNK 2048  // f4 elements of one W1 row per block (32KB)

typedef float f4 __attribute__((ext_vector_type(4)));

struct F3 { float x, y, z; };
__device__ inline F3 f3sub(F3 a, F3 b) { return {a.x - b.x, a.y - b.y, a.z - b.z}; }
__device__ inline F3 f3cross(F3 a, F3 b) {
    return {a.y * b.z - a.z * b.y, a.z * b.x - a.x * b.z, a.x * b.y - a.y * b.x};
}
__device__ inline float f3dot(F3 a, F3 b) { return a.x * b.x + a.y * b.y + a.z * b.z; }
__device__ inline F3 ldp(const float* __restrict__ p, int i) {
    return {p[3 * i], p[3 * i + 1], p[3 * i + 2]};
}
__device__ inline float dot4(f4 w, f4 v, float acc) {
    return fmaf(w.x, v.x, fmaf(w.y, v.y, fmaf(w.z, v.z, fmaf(w.w, v.w, acc))));
}

// Kernel 1: features x = [cos(angles) (A), cos(dih) (D), sin(dih) (D)]
__global__ __launch_bounds__(256) void feat_kernel(
    const float* __restrict__ pos, const int* __restrict__ aidx,
    const int* __restrict__ didx, float* __restrict__ x, int A, int D) {
    int i = blockIdx.x * blockDim.x + threadIdx.x;
    if (i < A) {
        int i0 = aidx[3 * i], i1 = aidx[3 * i + 1], i2 = aidx[3 * i + 2];
        F3 p0 = ldp(pos, i0), p1 = ldp(pos, i1), p2 = ldp(pos, i2);
        F3 v0 = f3sub(p0, p1), v1 = f3sub(p2, p1);
        float d = f3dot(v0, v1);
        F3 c = f3cross(v0, v1);
        float r = sqrtf(d * d + f3dot(c, c));   // = |v0||v1|
        x[i] = d / r;                            // cos(atan2(|c|, d))
    } else if (i < A + D) {
        int j = i - A;
        int i0 = didx[4 * j], i1 = didx[4 * j + 1], i2 = didx[4 * j + 2], i3 = didx[4 * j + 3];
        F3 p0 = ldp(pos, i0), p1 = ldp(pos, i1), p2 = ldp(pos, i2), p3 = ldp(pos, i3);
        F3 b1v = f3sub(p1, p0), b2v = f3sub(p2, p1), b3v = f3sub(p3, p2);
        F3 n1 = f3cross(b1v, b2v), n2 = f3cross(b2v, b3v);
        float xc = f3dot(n1, n2);                          // cos-like term
        float b2n = sqrtf(f3dot(b2v, b2v));
        F3 cr = f3cross(n1, n2);
        float yc = f3dot(cr, b2v) / b2n;                   // sin-like term
        float r = sqrtf(xc * xc + yc * yc);
        x[A + j] = xc / r;        // cos(dihedral)
        x[A + D + j] = yc / r;    // sin(dihedral)
    }
}

// Kernel 2: y1 partials, linear-sweep layout, 8-deep ILP, nontemporal W1
// (R8 A/B: nt is 2us faster — 307MB cyclic stream thrashes 256MB L3; nt
// keeps x/W2/W3 cache-resident instead).
__global__ __launch_bounds__(256) void w1_kernel(
    const float* __restrict__ W1, const float* __restrict__ x,
    float* __restrict__ partial, int F4, int NCH) {
    int c = blockIdx.x, r = blockIdx.y;
    const f4* __restrict__ row = (const f4*)W1 + (size_t)r * F4;
    const f4* __restrict__ xv = (const f4*)x;
    int base = c * CHUNK + (int)threadIdx.x;
    float a0 = 0.0f, a1 = 0.0f, a2 = 0.0f, a3 = 0.0f;
    float a4 = 0.0f, a5 = 0.0f, a6 = 0.0f, a7 = 0.0f;
    if (base + 1792 < F4) {  // full chunk fast path: 8 independent streams
        f4 w0 = __builtin_nontemporal_load(&row[base]);
        f4 w1 = __builtin_nontemporal_load(&row[base + 256]);
        f4 w2 = __builtin_nontemporal_load(&row[base + 512]);
        f4 w3 = __builtin_nontemporal_load(&row[base + 768]);
        f4 w4 = __builtin_nontemporal_load(&row[base + 1024]);
        f4 w5 = __builtin_nontemporal_load(&row[base + 1280]);
        f4 w6 = __builtin_nontemporal_load(&row[base + 1536]);
        f4 w7 = __builtin_nontemporal_load(&row[base + 1792]);
        a0 = dot4(w0, xv[base], a0);
        a1 = dot4(w1, xv[base + 256], a1);
        a2 = dot4(w2, xv[base + 512], a2);
        a3 = dot4(w3, xv[base + 768], a3);
        a4 = dot4(w4, xv[base + 1024], a4);
        a5 = dot4(w5, xv[base + 1280], a5);
        a6 = dot4(w6, xv[base + 1536], a6);
        a7 = dot4(w7, xv[base + 1792], a7);
    } else {
        #pragma unroll
        for (int u = 0; u < 8; ++u) {
            int i = base + u * 256;
            if (i < F4) a0 = dot4(__builtin_nontemporal_load(&row[i]), xv[i], a0);
        }
    }
    float acc = ((a0 + a1) + (a2 + a3)) + ((a4 + a5) + (a6 + a7));
    #pragma unroll
    for (int off = 32; off; off >>= 1) acc += __shfl_down(acc, off);
    __shared__ float lds[4];
    int wave = threadIdx.x >> 6, lane = threadIdx.x & 63;
    if (lane == 0) lds[wave] = acc;
    __syncthreads();
    if (threadIdx.x == 0) partial[r * NCH + c] = lds[0] + lds[1] + lds[2] + lds[3];
}

// Kernel 3: layer 2, one block per output row (parallel W2 fetch). Each block
// redundantly finishes layer 1 from L2-hot partials. Block 0 zeroes out[0]
// (runs strictly before l3 via stream ordering; also clears 0xAA poison).
__global__ __launch_bounds__(256) void l2_kernel(
    const float* __restrict__ partial, const float* __restrict__ b1,
    const float* __restrict__ W2, const float* __restrict__ b2,
    float* __restrict__ xb, float* __restrict__ out, int NCH) {
    __shared__ float xa[256];
    __shared__ float lds[4];
    int t = threadIdx.x, r = blockIdx.x;
    if (r == 0 && t == 0) out[0] = 0.0f;
    float s = 0.0f;
    #pragma unroll 8
    for (int c = 0; c < NCH; ++c) s += partial[t * NCH + c];
    xa[t] = tanhf(s + b1[t]);
    __syncthreads();
    float v = W2[(r << 8) + t] * xa[t];
    #pragma unroll
    for (int off = 32; off; off >>= 1) v += __shfl_down(v, off);
    if ((t & 63) == 0) lds[t >> 6] = v;
    __syncthreads();
    if (t == 0) xb[r] = tanhf(lds[0] + lds[1] + lds[2] + lds[3] + b2[r]);
}

// Kernel 4: layer 3 + W4 + final sum, fused. 64 blocks x 4 waves; wave w
// owns row r = blk*4+w. Lane l reads W3[r][4l..4l+3] as f4 (coalesced),
// wave-shuffle reduce, lane 0 atomicAdd's the KBT-scaled term into out[0].
// No LDS, no barriers, no fences; 256 adds to one address (trivial).
__global__ __launch_bounds__(256) void l3_kernel(
    const float* __restrict__ xb, const float* __restrict__ W3,
    const float* __restrict__ b3, const float* __restrict__ W4,
    float* __restrict__ out) {
    int t = threadIdx.x;
    int wave = t >> 6, lane = t & 63;
    int r = (blockIdx.x << 2) + wave;
    const f4* __restrict__ W3v = (const f4*)W3 + (r << 6);
    const f4* __restrict__ xv = (const f4*)xb;
    float v = dot4(W3v[lane], xv[lane], 0.0f);
    #pragma unroll
    for (int off = 32; off; off >>= 1) v += __shfl_down(v, off);
    if (lane == 0) {
        float y = KBT * W4[r] * tanhf(v + b3[r]);
        atomicAdd(out, y);
    }
}

extern "C" void kernel_launch(void* const* d_in, const int* in_sizes, int n_in,
                              void* d_out, int out_size, void* d_ws, size_t ws_size,
                              hipStream_t stream) {
    const float* pos  = (const float*)d_in[0];
    const int*   aidx = (const int*)d_in[1];
    const int*   didx = (const int*)d_in[2];
    const float* W1   = (const float*)d_in[3];
    const float* b1   = (const float*)d_in[4];
    const float* W2   = (const float*)d_in[5];
    const float* b2   = (const float*)d_in[6];
    const float* W3   = (const float*)d_in[7];
    const float* b3   = (const float*)d_in[8];
    const float* W4   = (const float*)d_in[9];

    int A = in_sizes[1] / 3;
    int D = in_sizes[2] / 4;
    int F = A + 2 * D;          // 299992, divisible by 4
    int F4 = F >> 2;            // 74998 f4 per row
    int NCH = (F4 + CHUNK - 1) / CHUNK;  // 37

    float* ws = (float*)d_ws;
    float* x = ws;                              // F floats
    float* partial = ws + ((F + 3) & ~3);       // 256*NCH floats
    float* xb = partial + 256 * NCH;            // 256 floats (16B-aligned)

    int total = A + D;
    feat_kernel<<<(total + 255) / 256, 256, 0, stream>>>(pos, aidx, didx, x, A, D);

    dim3 g(NCH, 256);  // chunk fastest -> linear HBM sweep over W1
    w1_kernel<<<g, 256, 0, stream>>>(W1, x, partial, F4, NCH);

    l2_kernel<<<256, 256, 0, stream>>>(partial, b1, W2, b2, xb,
                                       (float*)d_out, NCH);
    l3_kernel<<<64, 256, 0, stream>>>(xb, W3, b3, W4, (float*)d_out);
}

// Round 11
// 70.009 us; speedup vs baseline: 1.0801x; 1.0224x over previous
//
#include <hip/hip_runtime.h>
#include <math.h>

#define KBT 2.494338785445972f
#define CHUNK 2048  // f4 elements of one W1 row per block (32KB)

typedef float f4 __attribute__((ext_vector_type(4)));
typedef float f3v __attribute__((ext_vector_type(3), aligned(4)));
typedef int i3v __attribute__((ext_vector_type(3), aligned(4)));
typedef int i4v __attribute__((ext_vector_type(4), aligned(16)));

struct F3 { float x, y, z; };
__device__ inline F3 f3sub(F3 a, F3 b) { return {a.x - b.x, a.y - b.y, a.z - b.z}; }
__device__ inline F3 f3cross(F3 a, F3 b) {
    return {a.y * b.z - a.z * b.y, a.z * b.x - a.x * b.z, a.x * b.y - a.y * b.x};
}
__device__ inline float f3dot(F3 a, F3 b) { return a.x * b.x + a.y * b.y + a.z * b.z; }
__device__ inline F3 ldp3(const float* __restrict__ p, int i) {
    f3v v = *(const f3v*)(p + 3 * i);   // one global_load_dwordx3 (4B-aligned ok)
    return {v.x, v.y, v.z};
}
__device__ inline float dot4(f4 w, f4 v, float acc) {
    return fmaf(w.x, v.x, fmaf(w.y, v.y, fmaf(w.z, v.z, fmaf(w.w, v.w, acc))));
}

// Kernel 1: features x = [cos(angles) (A), cos(dih) (D), sin(dih) (D)]
// Vectorized gathers: dwordx3 position/angle-idx loads, dwordx4 dih-idx.
__global__ __launch_bounds__(256) void feat_kernel(
    const float* __restrict__ pos, const int* __restrict__ aidx,
    const int* __restrict__ didx, float* __restrict__ x, int A, int D) {
    int i = blockIdx.x * blockDim.x + threadIdx.x;
    if (i < A) {
        i3v idx = *(const i3v*)(aidx + 3 * i);
        F3 p0 = ldp3(pos, idx.x), p1 = ldp3(pos, idx.y), p2 = ldp3(pos, idx.z);
        F3 v0 = f3sub(p0, p1), v1 = f3sub(p2, p1);
        float d = f3dot(v0, v1);
        F3 c = f3cross(v0, v1);
        float r = sqrtf(d * d + f3dot(c, c));   // = |v0||v1|
        x[i] = d / r;                            // cos(atan2(|c|, d))
    } else if (i < A + D) {
        int j = i - A;
        i4v idx = *(const i4v*)(didx + 4 * j);
        F3 p0 = ldp3(pos, idx.x), p1 = ldp3(pos, idx.y);
        F3 p2 = ldp3(pos, idx.z), p3 = ldp3(pos, idx.w);
        F3 b1v = f3sub(p1, p0), b2v = f3sub(p2, p1), b3v = f3sub(p3, p2);
        F3 n1 = f3cross(b1v, b2v), n2 = f3cross(b2v, b3v);
        float xc = f3dot(n1, n2);                          // cos-like term
        float b2n = sqrtf(f3dot(b2v, b2v));
        F3 cr = f3cross(n1, n2);
        float yc = f3dot(cr, b2v) / b2n;                   // sin-like term
        float r = sqrtf(xc * xc + yc * yc);
        x[A + j] = xc / r;        // cos(dihedral)
        x[A + D + j] = yc / r;    // sin(dihedral)
    }
}

// Kernel 2: y1 partials, linear-sweep layout, 8-deep ILP, nontemporal W1
// (R8 A/B: nt is 2us faster — 307MB cyclic stream thrashes 256MB L3; nt
// keeps x/W2/W3 cache-resident instead).
__global__ __launch_bounds__(256) void w1_kernel(
    const float* __restrict__ W1, const float* __restrict__ x,
    float* __restrict__ partial, int F4, int NCH) {
    int c = blockIdx.x, r = blockIdx.y;
    const f4* __restrict__ row = (const f4*)W1 + (size_t)r * F4;
    const f4* __restrict__ xv = (const f4*)x;
    int base = c * CHUNK + (int)threadIdx.x;
    float a0 = 0.0f, a1 = 0.0f, a2 = 0.0f, a3 = 0.0f;
    float a4 = 0.0f, a5 = 0.0f, a6 = 0.0f, a7 = 0.0f;
    if (base + 1792 < F4) {  // full chunk fast path: 8 independent streams
        f4 w0 = __builtin_nontemporal_load(&row[base]);
        f4 w1 = __builtin_nontemporal_load(&row[base + 256]);
        f4 w2 = __builtin_nontemporal_load(&row[base + 512]);
        f4 w3 = __builtin_nontemporal_load(&row[base + 768]);
        f4 w4 = __builtin_nontemporal_load(&row[base + 1024]);
        f4 w5 = __builtin_nontemporal_load(&row[base + 1280]);
        f4 w6 = __builtin_nontemporal_load(&row[base + 1536]);
        f4 w7 = __builtin_nontemporal_load(&row[base + 1792]);
        a0 = dot4(w0, xv[base], a0);
        a1 = dot4(w1, xv[base + 256], a1);
        a2 = dot4(w2, xv[base + 512], a2);
        a3 = dot4(w3, xv[base + 768], a3);
        a4 = dot4(w4, xv[base + 1024], a4);
        a5 = dot4(w5, xv[base + 1280], a5);
        a6 = dot4(w6, xv[base + 1536], a6);
        a7 = dot4(w7, xv[base + 1792], a7);
    } else {
        #pragma unroll
        for (int u = 0; u < 8; ++u) {
            int i = base + u * 256;
            if (i < F4) a0 = dot4(__builtin_nontemporal_load(&row[i]), xv[i], a0);
        }
    }
    float acc = ((a0 + a1) + (a2 + a3)) + ((a4 + a5) + (a6 + a7));
    #pragma unroll
    for (int off = 32; off; off >>= 1) acc += __shfl_down(acc, off);
    __shared__ float lds[4];
    int wave = threadIdx.x >> 6, lane = threadIdx.x & 63;
    if (lane == 0) lds[wave] = acc;
    __syncthreads();
    if (threadIdx.x == 0) partial[r * NCH + c] = lds[0] + lds[1] + lds[2] + lds[3];
}

// Kernel 3: layer 2, one block per output row. Each block redundantly
// finishes layer 1 from L2-hot partials.
__global__ __launch_bounds__(256) void l2_kernel(
    const float* __restrict__ partial, const float* __restrict__ b1,
    const float* __restrict__ W2, const float* __restrict__ b2,
    float* __restrict__ xb, int NCH) {
    __shared__ float xa[256];
    __shared__ float lds[4];
    int t = threadIdx.x, r = blockIdx.x;
    float s = 0.0f;
    #pragma unroll 8
    for (int c = 0; c < NCH; ++c) s += partial[t * NCH + c];
    xa[t] = tanhf(s + b1[t]);
    __syncthreads();
    float v = W2[(r << 8) + t] * xa[t];
    #pragma unroll
    for (int off = 32; off; off >>= 1) v += __shfl_down(v, off);
    if ((t & 63) == 0) lds[t >> 6] = v;
    __syncthreads();
    if (t == 0) xb[r] = tanhf(lds[0] + lds[1] + lds[2] + lds[3] + b2[r]);
}

// Kernel 4: layer 3 + W4 elementwise, one block per row.
__global__ __launch_bounds__(256) void l3_kernel(
    const float* __restrict__ xb, const float* __restrict__ W3,
    const float* __restrict__ b3, const float* __restrict__ W4,
    float* __restrict__ w4term) {
    __shared__ float lds[4];
    int t = threadIdx.x, r = blockIdx.x;
    float v = W3[(r << 8) + t] * xb[t];
    #pragma unroll
    for (int off = 32; off; off >>= 1) v += __shfl_down(v, off);
    if ((t & 63) == 0) lds[t >> 6] = v;
    __syncthreads();
    if (t == 0) w4term[r] = W4[r] * tanhf(lds[0] + lds[1] + lds[2] + lds[3] + b3[r]);
}

// Kernel 5: final 256 -> scalar
__global__ __launch_bounds__(256) void out_kernel(
    const float* __restrict__ w4term, float* __restrict__ out) {
    __shared__ float lds[4];
    int t = threadIdx.x;
    float v = w4term[t];
    #pragma unroll
    for (int off = 32; off; off >>= 1) v += __shfl_down(v, off);
    if ((t & 63) == 0) lds[t >> 6] = v;
    __syncthreads();
    if (t == 0) out[0] = KBT * (lds[0] + lds[1] + lds[2] + lds[3]);
}

extern "C" void kernel_launch(void* const* d_in, const int* in_sizes, int n_in,
                              void* d_out, int out_size, void* d_ws, size_t ws_size,
                              hipStream_t stream) {
    const float* pos  = (const float*)d_in[0];
    const int*   aidx = (const int*)d_in[1];
    const int*   didx = (const int*)d_in[2];
    const float* W1   = (const float*)d_in[3];
    const float* b1   = (const float*)d_in[4];
    const float* W2   = (const float*)d_in[5];
    const float* b2   = (const float*)d_in[6];
    const float* W3   = (const float*)d_in[7];
    const float* b3   = (const float*)d_in[8];
    const float* W4   = (const float*)d_in[9];

    int A = in_sizes[1] / 3;
    int D = in_sizes[2] / 4;
    int F = A + 2 * D;          // 299992, divisible by 4
    int F4 = F >> 2;            // 74998 f4 per row
    int NCH = (F4 + CHUNK - 1) / CHUNK;  // 37

    float* ws = (float*)d_ws;
    float* x = ws;                              // F floats
    float* partial = ws + ((F + 3) & ~3);       // 256*NCH floats
    float* xb = partial + 256 * NCH;            // 256 floats
    float* w4term = xb + 256;                   // 256 floats

    int total = A + D;
    feat_kernel<<<(total + 255) / 256, 256, 0, stream>>>(pos, aidx, didx, x, A, D);

    dim3 g(NCH, 256);  // chunk fastest -> linear HBM sweep over W1
    w1_kernel<<<g, 256, 0, stream>>>(W1, x, partial, F4, NCH);

    l2_kernel<<<256, 256, 0, stream>>>(partial, b1, W2, b2, xb, NCH);
    l3_kernel<<<256, 256, 0, stream>>>(xb, W3, b3, W4, w4term);
    out_kernel<<<1, 256, 0, stream>>>(w4term, (float*)d_out);
}